// Round 1
// baseline (548.074 us; speedup 1.0000x reference)
//
#include <hip/hip_runtime.h>

#define B 32
#define M 4096
#define N 8192
#define DC 10
#define NUM_ITERS 8
#define INV_TEMP 100.0f   // 1/TEMP, TEMP=0.01
#define ALPHA 100.0f

// One thread per (b, m) check node.
// v2c is computed on the fly: iter==0 -> prior[nbr]; else llrs[b,nbr] - c2v_prev.
// Writes new c2v and atomically scatters into accum (B,N).
__global__ __launch_bounds__(256) void check_kernel(
    const float* __restrict__ syn,    // (B,M)
    const float* __restrict__ prior,  // (N,)
    const int*   __restrict__ nbrs,   // (M,DC)
    const float* __restrict__ llrs,   // (B,N)  (prev llrs; unused when iter==0)
    float*       __restrict__ c2v,    // (B,M,DC)
    float*       __restrict__ accum,  // (B,N)  (must be zeroed before)
    int iter)
{
    int idx = blockIdx.x * blockDim.x + threadIdx.x;   // b*M + m
    if (idx >= B * M) return;
    int b = idx / M;
    int m = idx - b * M;

    const int* nr = nbrs + (size_t)m * DC;
    float* c2vp = c2v + (size_t)idx * DC;

    int nb[DC];
    #pragma unroll
    for (int i = 0; i < DC; ++i) nb[i] = nr[i];

    float v[DC];
    if (iter == 0) {
        #pragma unroll
        for (int i = 0; i < DC; ++i) v[i] = prior[nb[i]];
    } else {
        const float* lb = llrs + (size_t)b * N;
        #pragma unroll
        for (int i = 0; i < DC; ++i) v[i] = lb[nb[i]] - c2vp[i];
    }

    float s[DC], a[DC];
    #pragma unroll
    for (int i = 0; i < DC; ++i) {
        s[i] = tanhf(ALPHA * v[i]);   // smooth_sign
        a[i] = fabsf(v[i]);
    }

    // two smallest |v| and argmin
    float min1 = 3.4e38f, min2 = 3.4e38f;
    int am = 0;
    #pragma unroll
    for (int i = 0; i < DC; ++i) {
        if (a[i] < min1) { min2 = min1; min1 = a[i]; am = i; }
        else if (a[i] < min2) { min2 = a[i]; }
    }

    // prefix/suffix sign products for leave-one-out product
    float pre[DC + 1], suf[DC + 1];
    pre[0] = 1.0f;
    #pragma unroll
    for (int i = 0; i < DC; ++i) pre[i + 1] = pre[i] * s[i];
    suf[DC] = 1.0f;
    #pragma unroll
    for (int i = DC - 1; i >= 0; --i) suf[i] = suf[i + 1] * s[i];

    // softmin sums shifted by global min1 (w[am] == 1 exactly)
    float w[DC];
    float se = 0.0f, sae = 0.0f;
    #pragma unroll
    for (int i = 0; i < DC; ++i) {
        w[i] = expf((min1 - a[i]) * INV_TEMP);
        se  += w[i];
        sae += a[i] * w[i];
    }

    float ssgn = 1.0f - 2.0f * syn[idx];

    #pragma unroll
    for (int i = 0; i < DC; ++i) {
        float me;
        if (i == am) {
            // leave-one-out excluding the argmin: shift by min2
            float se2 = 0.0f, sae2 = 0.0f;
            #pragma unroll
            for (int j = 0; j < DC; ++j) {
                if (j == am) continue;
                float wj = expf((min2 - a[j]) * INV_TEMP);
                se2  += wj;
                sae2 += a[j] * wj;
            }
            me = sae2 / se2;
        } else {
            me = (sae - a[i] * w[i]) / (se - w[i]);
        }
        float out = ssgn * (pre[i] * suf[i + 1]) * me;
        c2vp[i] = out;
        atomicAdd(accum + (size_t)b * N + nb[i], out);
    }
}

// One thread per (b, n). Consumes accum (re-zeroing it for the next iteration)
// and produces the new llrs.
__global__ __launch_bounds__(256) void var_kernel(
    const float* __restrict__ prior,   // (N,)
    const float* __restrict__ gamma,   // (N,)
    float*       __restrict__ accum,   // (B,N), zeroed after read
    const float* __restrict__ llrs_in, // (B,N) prev llrs (unused when iter==0)
    float*       __restrict__ llrs_out,// (B,N)
    int iter)
{
    int idx = blockIdx.x * blockDim.x + threadIdx.x;   // b*N + n
    if (idx >= B * N) return;
    int n = idx & (N - 1);

    float acc = accum[idx];
    accum[idx] = 0.0f;                 // ready for next iteration
    float p = prior[n];
    float o;
    if (iter == 0) {
        o = acc + p;
    } else {
        float g = gamma[n];
        o = acc + (1.0f - g) * p + g * llrs_in[idx];
    }
    llrs_out[idx] = o;
}

extern "C" void kernel_launch(void* const* d_in, const int* in_sizes, int n_in,
                              void* d_out, int out_size, void* d_ws, size_t ws_size,
                              hipStream_t stream) {
    const float* syn   = (const float*)d_in[0];   // (B,M)
    const float* prior = (const float*)d_in[1];   // (N,)
    const float* gamma = (const float*)d_in[2];   // (N,)
    const int*   nbrs  = (const int*)d_in[3];     // (M,DC)
    float* out = (float*)d_out;                   // (B,N)

    float* accum = (float*)d_ws;                  // B*N
    float* llrs  = accum + (size_t)B * N;         // B*N
    float* c2v   = llrs + (size_t)B * N;          // B*M*DC

    // clear accumulator (covers the one-time 0xAA poison; var_kernel keeps it
    // zeroed afterwards, so this is cheap insurance every call)
    hipMemsetAsync(accum, 0, (size_t)B * N * sizeof(float), stream);

    const int cthreads = B * M;
    const int vthreads = B * N;
    dim3 blk(256);
    dim3 cgrid((cthreads + 255) / 256);
    dim3 vgrid((vthreads + 255) / 256);

    for (int t = 0; t < NUM_ITERS; ++t) {
        check_kernel<<<cgrid, blk, 0, stream>>>(syn, prior, nbrs, llrs, c2v, accum, t);
        float* lo = (t == NUM_ITERS - 1) ? out : llrs;
        var_kernel<<<vgrid, blk, 0, stream>>>(prior, gamma, accum, llrs, lo, t);
    }
}

// Round 2
// 118.506 us; speedup vs baseline: 4.6249x; 4.6249x over previous
//
#include <hip/hip_runtime.h>

#define B 32
#define M 4096
#define N 8192
#define DC 10
#define NUM_ITERS 8
#define INV_TEMP 100.0f   // 1/TEMP, TEMP=0.01
#define ALPHA 100.0f

// Transpose syndromes (B,M) -> sign form (M,B): syn_t[m*B+b] = 1-2*syn[b*M+m]
__global__ __launch_bounds__(256) void syn_transpose_kernel(
    const float* __restrict__ syn, float* __restrict__ syn_t)
{
    int idx = blockIdx.x * blockDim.x + threadIdx.x;  // m*B + b
    if (idx >= B * M) return;
    int b = idx & (B - 1);
    int m = idx >> 5;
    syn_t[idx] = 1.0f - 2.0f * syn[(size_t)b * M + m];
}

// One thread per (m, b) with b innermost: lanes 0..31 share m -> all gathers,
// c2v accesses and atomics are coalesced (32 consecutive 4B addresses).
__global__ __launch_bounds__(256) void check_kernel(
    const float* __restrict__ syn_t,  // (M,B) sign form
    const float* __restrict__ prior,  // (N,)
    const int*   __restrict__ nbrs,   // (M,DC)
    const float* __restrict__ llrs,   // (N,B)  prev llrs (unused iter 0)
    float*       __restrict__ c2v,    // (M,DC,B)
    float*       __restrict__ accum,  // (N,B)  zeroed before
    int iter)
{
    int idx = blockIdx.x * blockDim.x + threadIdx.x;  // m*B + b
    if (idx >= B * M) return;
    int b = idx & (B - 1);
    int m = idx >> 5;

    const int* nr = nbrs + (size_t)m * DC;
    float* c2vp = c2v + (size_t)m * DC * B + b;       // stride B between edges

    int nb[DC];
    #pragma unroll
    for (int i = 0; i < DC; ++i) nb[i] = nr[i];       // same addr across 32 lanes -> broadcast

    float v[DC];
    if (iter == 0) {
        #pragma unroll
        for (int i = 0; i < DC; ++i) v[i] = prior[nb[i]];
    } else {
        #pragma unroll
        for (int i = 0; i < DC; ++i) v[i] = llrs[(size_t)nb[i] * B + b] - c2vp[(size_t)i * B];
    }

    float s[DC], a[DC];
    #pragma unroll
    for (int i = 0; i < DC; ++i) {
        s[i] = tanhf(ALPHA * v[i]);   // smooth_sign
        a[i] = fabsf(v[i]);
    }

    // two smallest |v| and argmin
    float min1 = 3.4e38f, min2 = 3.4e38f;
    int am = 0;
    #pragma unroll
    for (int i = 0; i < DC; ++i) {
        if (a[i] < min1) { min2 = min1; min1 = a[i]; am = i; }
        else if (a[i] < min2) { min2 = a[i]; }
    }

    // prefix/suffix sign products for leave-one-out product
    float pre[DC + 1], suf[DC + 1];
    pre[0] = 1.0f;
    #pragma unroll
    for (int i = 0; i < DC; ++i) pre[i + 1] = pre[i] * s[i];
    suf[DC] = 1.0f;
    #pragma unroll
    for (int i = DC - 1; i >= 0; --i) suf[i] = suf[i + 1] * s[i];

    // softmin sums shifted by global min1 (w[am] == 1 exactly)
    float w[DC];
    float se = 0.0f, sae = 0.0f;
    #pragma unroll
    for (int i = 0; i < DC; ++i) {
        w[i] = expf((min1 - a[i]) * INV_TEMP);
        se  += w[i];
        sae += a[i] * w[i];
    }

    float ssgn = syn_t[idx];

    #pragma unroll
    for (int i = 0; i < DC; ++i) {
        float me;
        if (i == am) {
            // leave-one-out excluding the argmin: shift by min2
            float se2 = 0.0f, sae2 = 0.0f;
            #pragma unroll
            for (int j = 0; j < DC; ++j) {
                if (j == am) continue;
                float wj = expf((min2 - a[j]) * INV_TEMP);
                se2  += wj;
                sae2 += a[j] * wj;
            }
            me = sae2 / se2;
        } else {
            me = (sae - a[i] * w[i]) / (se - w[i]);
        }
        float out = ssgn * (pre[i] * suf[i + 1]) * me;
        c2vp[(size_t)i * B] = out;
        atomicAdd(accum + (size_t)nb[i] * B + b, out);
    }
}

// One thread per (n, b), b innermost. Consumes accum (re-zeroing for next
// iteration). Writes llrs (N,B); on the final iteration writes d_out (B,N).
__global__ __launch_bounds__(256) void var_kernel(
    const float* __restrict__ prior,   // (N,)
    const float* __restrict__ gamma,   // (N,)
    float*       __restrict__ accum,   // (N,B)
    const float* __restrict__ llrs_in, // (N,B)
    float*       __restrict__ llrs_out,// (N,B)
    float*       __restrict__ final_out, // (B,N) or nullptr
    int iter)
{
    int idx = blockIdx.x * blockDim.x + threadIdx.x;  // n*B + b
    if (idx >= B * N) return;
    int b = idx & (B - 1);
    int n = idx >> 5;

    float acc = accum[idx];
    accum[idx] = 0.0f;                 // ready for next iteration
    float p = prior[n];
    float o;
    if (iter == 0) {
        o = acc + p;
    } else {
        float g = gamma[n];
        o = acc + (1.0f - g) * p + g * llrs_in[idx];
    }
    if (final_out) {
        final_out[(size_t)b * N + n] = o;   // one-time transposed write (1 MB)
    } else {
        llrs_out[idx] = o;
    }
}

extern "C" void kernel_launch(void* const* d_in, const int* in_sizes, int n_in,
                              void* d_out, int out_size, void* d_ws, size_t ws_size,
                              hipStream_t stream) {
    const float* syn   = (const float*)d_in[0];   // (B,M)
    const float* prior = (const float*)d_in[1];   // (N,)
    const float* gamma = (const float*)d_in[2];   // (N,)
    const int*   nbrs  = (const int*)d_in[3];     // (M,DC)
    float* out = (float*)d_out;                   // (B,N)

    float* accum = (float*)d_ws;                  // N*B
    float* llrs  = accum + (size_t)N * B;         // N*B
    float* c2v   = llrs + (size_t)N * B;          // M*DC*B
    float* syn_t = c2v + (size_t)M * DC * B;      // M*B

    // clear accumulator (covers the one-time 0xAA poison; var_kernel keeps it
    // zeroed afterwards)
    hipMemsetAsync(accum, 0, (size_t)N * B * sizeof(float), stream);

    const int cthreads = B * M;
    const int vthreads = B * N;
    dim3 blk(256);
    dim3 cgrid((cthreads + 255) / 256);
    dim3 vgrid((vthreads + 255) / 256);

    syn_transpose_kernel<<<cgrid, blk, 0, stream>>>(syn, syn_t);

    for (int t = 0; t < NUM_ITERS; ++t) {
        check_kernel<<<cgrid, blk, 0, stream>>>(syn_t, prior, nbrs, llrs, c2v, accum, t);
        float* fo = (t == NUM_ITERS - 1) ? out : nullptr;
        var_kernel<<<vgrid, blk, 0, stream>>>(prior, gamma, accum, llrs, llrs, fo, t);
    }
}

// Round 5
// 94.348 us; speedup vs baseline: 5.8090x; 1.2560x over previous
//
#include <hip/hip_runtime.h>

#define B 32
#define M 4096
#define N 8192
#define DC 10
#define NUM_ITERS 8
#define INV_TEMP 100.0f   // 1/TEMP, TEMP=0.01
#define ALPHA 100.0f
#define NB (N * B)        // 262144
#define MB (M * B)        // 131072

// Prologue: zero accum A0, init BOTH llrs buffers to prior (degree-0 variables
// are never touched by any check; their correct llrs_t == prior for all t, and
// final_kernel reads llrs_6 for ALL n — this was the R3/R4 absmax-0.78 bug),
// build syn sign (M,B), build pg[n] = (1-gamma)*prior.
__global__ __launch_bounds__(256) void prologue_kernel(
    const float* __restrict__ syn,    // (B,M)
    const float* __restrict__ prior,  // (N,)
    const float* __restrict__ gamma,  // (N,)
    float* __restrict__ accumA,       // (N,B)
    float* __restrict__ L0,           // (N,B)
    float* __restrict__ L1,           // (N,B)
    float* __restrict__ syn_t,        // (M,B)
    float* __restrict__ pg)           // (N,)
{
    int idx = blockIdx.x * blockDim.x + threadIdx.x;
    if (idx < NB) {
        float p = prior[idx >> 5];
        accumA[idx] = 0.0f;
        L0[idx] = p;
        L1[idx] = p;
    }
    if (idx < MB) {
        int b = idx & 31, m = idx >> 5;
        syn_t[idx] = 1.0f - 2.0f * syn[(size_t)b * M + m];
    }
    if (idx < N) pg[idx] = (1.0f - gamma[idx]) * prior[idx];
}

// Fused check+var kernel. One thread per (m,b), b innermost (coalesced).
// KIND 0: t=0   v2c = prior[nb]
// KIND 1: t=1   llrs_0 = R + prior; v2c = llrs_0 - c2v; write Lnew
// KIND 2: t>=2  llrs   = R + pg + gamma*Lold; v2c = llrs - c2v; write Lnew
template <int KIND>
__global__ __launch_bounds__(256) void check_kernel(
    const float* __restrict__ syn_t,  // (M,B) sign form
    const float* __restrict__ prior,  // (N,)
    const float* __restrict__ pg,     // (N,)
    const float* __restrict__ gamma,  // (N,)
    const int*   __restrict__ nbrs,   // (M,DC)
    const float* __restrict__ R,      // accum_{t-1} (N,B)
    float*       __restrict__ W,      // accum_t (N,B), pre-zeroed
    float*       __restrict__ Z,      // accum buffer zeroed here for t+1
    const float* __restrict__ Lold,   // llrs_{t-2} (N,B)
    float*       __restrict__ Lnew,   // llrs_{t-1} (N,B)
    float*       __restrict__ c2v)    // (M,DC,B)
{
    int idx = blockIdx.x * blockDim.x + threadIdx.x;  // m*B + b
    if (idx >= MB) return;
    const int b = idx & 31;
    const int m = idx >> 5;

    // zero next iteration's accumulator (2 elements per thread)
    Z[idx] = 0.0f;
    Z[idx + MB] = 0.0f;

    const int* nr = nbrs + m * DC;
    float* c2vp = c2v + (size_t)(m * DC) * B + b;

    int nb[DC];
    #pragma unroll
    for (int i = 0; i < DC; ++i) nb[i] = nr[i];   // broadcast across lanes

    float v[DC];
    if (KIND == 0) {
        #pragma unroll
        for (int i = 0; i < DC; ++i) v[i] = prior[nb[i]];
    } else if (KIND == 1) {
        #pragma unroll
        for (int i = 0; i < DC; ++i) {
            int g = nb[i] * B + b;
            float l = R[g] + prior[nb[i]];
            Lnew[g] = l;                           // redundant identical writes: benign
            v[i] = l - c2vp[(size_t)i * B];
        }
    } else {
        #pragma unroll
        for (int i = 0; i < DC; ++i) {
            int g = nb[i] * B + b;
            float l = R[g] + pg[nb[i]] + gamma[nb[i]] * Lold[g];
            Lnew[g] = l;
            v[i] = l - c2vp[(size_t)i * B];
        }
    }

    float s[DC], a[DC];
    #pragma unroll
    for (int i = 0; i < DC; ++i) {
        s[i] = tanhf(ALPHA * v[i]);   // smooth_sign (libm precision)
        a[i] = fabsf(v[i]);
    }

    // two smallest |v| and argmin
    float min1 = 3.4e38f, min2 = 3.4e38f;
    int am = 0;
    #pragma unroll
    for (int i = 0; i < DC; ++i) {
        if (a[i] < min1) { min2 = min1; min1 = a[i]; am = i; }
        else if (a[i] < min2) { min2 = a[i]; }
    }

    // prefix/suffix sign products for leave-one-out product
    float pre[DC + 1], suf[DC + 1];
    pre[0] = 1.0f;
    #pragma unroll
    for (int i = 0; i < DC; ++i) pre[i + 1] = pre[i] * s[i];
    suf[DC] = 1.0f;
    #pragma unroll
    for (int i = DC - 1; i >= 0; --i) suf[i] = suf[i + 1] * s[i];

    // softmin sums shifted by min1 (w[am] == 1 exactly)
    float w[DC];
    float se = 0.0f, sae = 0.0f;
    #pragma unroll
    for (int i = 0; i < DC; ++i) {
        w[i] = expf((min1 - a[i]) * INV_TEMP);
        se  += w[i];
        sae += a[i] * w[i];
    }

    // uniform (branchless) min2-shifted sums for the argmin edge's LOO softmin
    float se2 = 0.0f, sae2 = 0.0f;
    #pragma unroll
    for (int j = 0; j < DC; ++j) {
        float e2 = expf((min2 - a[j]) * INV_TEMP);
        e2 = (j != am) ? e2 : 0.0f;
        se2  += e2;
        sae2 += a[j] * e2;
    }
    float me_am = sae2 / se2;

    float ssgn = syn_t[idx];

    #pragma unroll
    for (int i = 0; i < DC; ++i) {
        float me = (i == am) ? me_am : (sae - a[i] * w[i]) / (se - w[i]);
        float out = ssgn * (pre[i] * suf[i + 1]) * me;
        c2vp[(size_t)i * B] = out;
        atomicAdd(&W[nb[i] * B + b], out);
    }
}

// Epilogue: llrs_7 = accum_7 + pg + gamma*llrs_6, written transposed to d_out (B,N).
__global__ __launch_bounds__(256) void final_kernel(
    const float* __restrict__ R,     // accum_7 (N,B)
    const float* __restrict__ pg,    // (N,)
    const float* __restrict__ gamma, // (N,)
    const float* __restrict__ Lold,  // llrs_6 (N,B)
    float*       __restrict__ out)   // (B,N)
{
    int idx = blockIdx.x * blockDim.x + threadIdx.x;  // b*N + n (write-coalesced)
    if (idx >= NB) return;
    int n = idx & (N - 1);
    int b = idx >> 13;
    int goff = n * B + b;
    out[idx] = R[goff] + pg[n] + gamma[n] * Lold[goff];
}

extern "C" void kernel_launch(void* const* d_in, const int* in_sizes, int n_in,
                              void* d_out, int out_size, void* d_ws, size_t ws_size,
                              hipStream_t stream) {
    const float* syn   = (const float*)d_in[0];   // (B,M)
    const float* prior = (const float*)d_in[1];   // (N,)
    const float* gamma = (const float*)d_in[2];   // (N,)
    const int*   nbrs  = (const int*)d_in[3];     // (M,DC)
    float* out = (float*)d_out;                   // (B,N)

    float* ws = (float*)d_ws;
    float* A[3] = { ws, ws + NB, ws + 2 * (size_t)NB };          // accum rotation
    float* L[2] = { ws + 3 * (size_t)NB, ws + 4 * (size_t)NB };  // llrs double buffer
    float* c2v   = ws + 5 * (size_t)NB;                          // M*DC*B
    float* syn_t = c2v + (size_t)M * DC * B;                     // M*B
    float* pg    = syn_t + MB;                                   // N

    dim3 blk256(256);
    dim3 pgrid((NB + 255) / 256);
    dim3 cgrid((MB + 255) / 256);

    prologue_kernel<<<pgrid, blk256, 0, stream>>>(syn, prior, gamma, A[0], L[0], L[1], syn_t, pg);

    for (int t = 0; t < NUM_ITERS; ++t) {
        float* Rb = A[(t + 2) % 3];
        float* Wb = A[t % 3];
        float* Zb = A[(t + 1) % 3];
        float* Lo = L[t & 1];          // llrs_{t-2}
        float* Ln = L[(t + 1) & 1];    // llrs_{t-1}
        if (t == 0) {
            check_kernel<0><<<cgrid, blk256, 0, stream>>>(syn_t, prior, pg, gamma, nbrs,
                                                          nullptr, Wb, Zb, nullptr, nullptr, c2v);
        } else if (t == 1) {
            check_kernel<1><<<cgrid, blk256, 0, stream>>>(syn_t, prior, pg, gamma, nbrs,
                                                          Rb, Wb, Zb, nullptr, Ln, c2v);
        } else {
            check_kernel<2><<<cgrid, blk256, 0, stream>>>(syn_t, prior, pg, gamma, nbrs,
                                                          Rb, Wb, Zb, Lo, Ln, c2v);
        }
    }
    // after t=7: accum_7 = A[7%3] = A[1], llrs_6 = L[(7+1)&1] = L[0]
    final_kernel<<<pgrid, blk256, 0, stream>>>(A[1], pg, gamma, L[0], out);
}